// Round 10
// baseline (80.824 us; speedup 1.0000x reference)
//
#include <hip/hip_runtime.h>

// ImprovedBilateralFilter3D — 96^3 fp32, v7: two-kernel cache-reliant split.
//
// Evidence (r3..r9): fused LDS variants are pinned at ~27 us kernel time
// regardless of LDS-read count (216 b32 -> 36 b128) or exp cost -> the cost
// is the barrier-serialized 3-stage structure + limited residency, not
// instruction issue. v7 removes LDS and barriers completely and relies on
// L1/L2/L3 (vol 3.5 MB, gv 14 MB — both cache-resident).
//
//   K1 sobel_pack: per-voxel separable Sobel (27 clustered global reads,
//      zero-pad) -> float4{gh,gw,gd,val} into d_ws. 884k threads.
//   K2 bilateral:  per-voxel 27 float4 reads (x-contiguous, coalesced,
//      L1-overlapping across dx), edge-clamped; one exp2 per neighbor with
//      log2(e) and spatial term folded at compile time. 884k threads.
// No __shared__, no __syncthreads, no launch_bounds min-waves (r5 lesson).

#define NV 96
#define NV2 (NV * NV)
#define NV3 (NV * NV * NV)

#define LOG2E 1.44269504088896340736f

__global__ __launch_bounds__(256) void sobel_pack_kernel(
    const float* __restrict__ vol, float4* __restrict__ gv) {
    int idx = blockIdx.x * blockDim.x + threadIdx.x;
    if (idx >= NV3) return;
    int x = idx % NV;
    int y = (idx / NV) % NV;
    int z = idx / NV2;

    float sz = 0.f, s1 = 0.f, s2 = 0.f;  // placeholder names unused
    (void)sz; (void)s1; (void)s2;

    // separable per-thread: for each (a=z-off, b=y-off) row, read 3 x-values
    // (zero outside bounds), reduce in x, then combine with z/y weights.
    float acc_ss = 0.f;  // not needed; direct accumulation below
    (void)acc_ss;

    float gh = 0.f, gw = 0.f, gd = 0.f;
#pragma unroll
    for (int a = 0; a < 3; ++a) {  // dz = a-1
        int zz = z + a - 1;
        bool zok = (zz >= 0) && (zz < NV);
        const float sma = (a == 1) ? 0.5f : 0.25f;
        const float dva = (a == 0) ? 1.0f : ((a == 2) ? -1.0f : 0.0f);
#pragma unroll
        for (int b = 0; b < 3; ++b) {  // dy = b-1
            int yy = y + b - 1;
            bool rok = zok && (yy >= 0) && (yy < NV);
            const float smb = (b == 1) ? 0.5f : 0.25f;
            const float dvb = (b == 0) ? 1.0f : ((b == 2) ? -1.0f : 0.0f);
            int rowbase = zz * NV2 + yy * NV + x;
            float v0 = (rok && x >= 1) ? vol[rowbase - 1] : 0.f;
            float v1 = rok ? vol[rowbase] : 0.f;
            float v2 = (rok && x < NV - 1) ? vol[rowbase + 1] : 0.f;
            float xs = 0.25f * v0 + 0.5f * v1 + 0.25f * v2;  // smooth x
            float xd = v0 - v2;                              // deriv x
            gh += dva * smb * xs;  // deriv z, smooth y, smooth x
            gw += sma * dvb * xs;  // smooth z, deriv y, smooth x
            gd += sma * smb * xd;  // smooth z, smooth y, deriv x
        }
    }
    gv[idx] = make_float4(gh, gw, gd, vol[idx]);
}

__global__ __launch_bounds__(256) void bilateral_kernel(
    const float4* __restrict__ gv, float* __restrict__ out) {
    int idx = blockIdx.x * blockDim.x + threadIdx.x;
    if (idx >= NV3) return;
    int x = idx % NV;
    int y = (idx / NV) % NV;
    int z = idx / NV2;

    const float RC = LOG2E / (2.0f * 1.2f * 1.2f);  // range coeff (log2e folded)

    float4 c = gv[idx];

    // edge-clamped coords
    int nx[3], ny[3], nz[3];
#pragma unroll
    for (int d = 0; d < 3; ++d) {
        nx[d] = min(max(x + d - 1, 0), NV - 1);
        ny[d] = min(max(y + d - 1, 0), NV - 1);
        nz[d] = min(max(z + d - 1, 0), NV - 1);
    }

    float num = 0.f, den = 0.f;
#pragma unroll
    for (int a = 0; a < 3; ++a) {
#pragma unroll
        for (int b = 0; b < 3; ++b) {
            int rowbase = nz[a] * NV2 + ny[b] * NV;
#pragma unroll
            for (int d = 0; d < 3; ++d) {
                // spatial term, compile-time, log2(e) pre-folded
                const float SDC =
                    -(float)((a - 1) * (a - 1) + (b - 1) * (b - 1) +
                             (d - 1) * (d - 1)) *
                    (LOG2E / (2.0f * 120.0f * 120.0f));
                float4 q = gv[rowbase + nx[d]];
                float dx_ = c.x - q.x, dy_ = c.y - q.y, dz_ = c.z - q.z;
                float g = dx_ * dx_ + dy_ * dy_ + dz_ * dz_;
                float w = __builtin_amdgcn_exp2f(fmaf(-g, RC, SDC));
                num += w * q.w;
                den += w;
            }
        }
    }
    out[idx] = num / fmaxf(den, 1e-8f);
}

extern "C" void kernel_launch(void* const* d_in, const int* in_sizes, int n_in,
                              void* d_out, int out_size, void* d_ws, size_t ws_size,
                              hipStream_t stream) {
    const float* vol = (const float*)d_in[0];
    float* out = (float*)d_out;
    float4* gv = (float4*)d_ws;  // 96^3 float4 = 14.2 MB

    const int threads = 256;
    const int blocks = (NV3 + threads - 1) / threads;  // 3456

    sobel_pack_kernel<<<blocks, threads, 0, stream>>>(vol, gv);
    bilateral_kernel<<<blocks, threads, 0, stream>>>(gv, out);
}

// Round 11
// 73.622 us; speedup vs baseline: 1.0978x; 1.0978x over previous
//
#include <hip/hip_runtime.h>

// ImprovedBilateralFilter3D — 96^3 fp32, v8: single kernel, single barrier.
//
// Evidence r3-r10: instruction cuts don't move the fused kernel (~27 us);
// split kernels are worse (~35 us). Remaining suspects: residency tail
// (28.8 KB LDS = 5 blocks/CU vs 6.75 needed) and the 2-barrier serial
// chain. v8 deletes the volume LDS tile: Sobel is computed directly from
// global (vol is L2-resident, rows coalesce) into the packed sq tile.
// LDS 19.6 KB -> 8 blocks/CU by LDS; grid ~fully co-resident; 1 barrier.
//
// Per block: 32x4x4 output tile, 256 threads.
//   Stage B': separable Sobel plane-sweep from GLOBAL (zero-pad), one
//             thread per (x,y) of the 34x6 grad patch, 8 z-planes,
//             rolling z-registers -> sq float4{gh,gw,gd,val}.
//   Stage C:  bilateral from sq; 2 adjacent voxels/thread; one exp2 per
//             neighbor, log2(e)+spatial folded at compile time. (= v6)

#define NV 96
#define NV2 (NV * NV)

#define TX 32
#define TY 4
#define TZ 4
#define GX (TX + 2)  // 34
#define GY (TY + 2)  // 6
#define GZ (TZ + 2)  // 6
#define NCOL (GX * GY)  // 204

#define LOG2E 1.44269504088896340736f

__global__ __launch_bounds__(256) void fused_bilateral_kernel(
    const float* __restrict__ vol, float* __restrict__ out) {
    __shared__ float4 sq[GZ][GY][GX];  // {gh, gw, gd, val} — 19584 B

    const int X0 = blockIdx.x * TX;
    const int Y0 = blockIdx.y * TY;
    const int Z0 = blockIdx.z * TZ;
    const int t = threadIdx.x;

    // ---- Stage B': separable Sobel from global, z plane-sweep ----
    if (t < NCOL) {
        const int gx_ = t % GX;
        const int gy_ = t / GX;
        const int gxg = X0 - 1 + gx_;  // global x of this grad column
        const int gyg = Y0 - 1 + gy_;  // global y
        const bool xok0 = (gxg - 1 >= 0) && (gxg - 1 < NV);
        const bool xok1 = (gxg >= 0) && (gxg < NV);
        const bool xok2 = (gxg + 1 >= 0) && (gxg + 1 < NV);

        float s0 = 0.f, s1 = 0.f, s2 = 0.f;  // sm_y (x) sm_x per plane
        float w0 = 0.f, w1 = 0.f, w2 = 0.f;  // dy (x) sm_x
        float u0 = 0.f, u1 = 0.f, u2 = 0.f;  // sm_y (x) dx
        float v11p = 0.f;                    // prev-plane center value
#pragma unroll
        for (int p = 0; p < 8; ++p) {
            const int zp = Z0 - 2 + p;
            const bool zok = (zp >= 0) && (zp < NV);
            float r[3], dxr[3], a11 = 0.f;
#pragma unroll
            for (int b = 0; b < 3; ++b) {
                const int yg = gyg + b - 1;
                const bool rok = zok && (yg >= 0) && (yg < NV);
                const float* row = vol + (zp * NV2 + yg * NV);
                float a0 = (rok && xok0) ? row[gxg - 1] : 0.f;
                float a1 = (rok && xok1) ? row[gxg] : 0.f;
                float a2 = (rok && xok2) ? row[gxg + 1] : 0.f;
                r[b] = 0.25f * a0 + 0.5f * a1 + 0.25f * a2;  // x-smooth
                dxr[b] = a0 - a2;                            // x-deriv
                if (b == 1) a11 = a1;
            }
            float sxy = 0.25f * r[0] + 0.5f * r[1] + 0.25f * r[2];
            float dyx = r[0] - r[2];
            float dxs = 0.25f * dxr[0] + 0.5f * dxr[1] + 0.25f * dxr[2];
            s0 = s1; s1 = s2; s2 = sxy;
            w0 = w1; w1 = w2; w2 = dyx;
            u0 = u1; u1 = u2; u2 = dxs;
            if (p >= 2) {
                float gh = s0 - s2;                              // deriv z
                float gw = 0.25f * w0 + 0.5f * w1 + 0.25f * w2;  // sm_z dy
                float gd = 0.25f * u0 + 0.5f * u1 + 0.25f * u2;  // sm_z dx
                sq[p - 2][gy_][gx_] = make_float4(gh, gw, gd, v11p);
            }
            v11p = a11;
        }
    }
    __syncthreads();

    // ---- Stage C: bilateral, 2 ADJACENT voxels/thread (2*tzh, 2*tzh+1) ----
    const int tx = t & 31;
    const int ty = (t >> 5) & 3;
    const int tzh = t >> 7;  // 0..1

    const float RC = LOG2E / (2.0f * 1.2f * 1.2f);  // range, log2e folded

    const int ox = X0 + tx;
    const int oy = Y0 + ty;
    const int oz0 = Z0 + tzh * 2;
    const int oz1 = oz0 + 1;

    // center packed grads: grad-local = tile-local + 1
    const float4 c0 = sq[tzh * 2 + 1][ty + 1][tx + 1];
    const float4 c1 = sq[tzh * 2 + 2][ty + 1][tx + 1];

    // clamped grad-local coords; 4 shared z-planes cover both voxels
    int nx[3], ny[3], nz[4];
#pragma unroll
    for (int d = 0; d < 3; ++d) {
        nx[d] = min(max(ox + d - 1, 0), NV - 1) - (X0 - 1);
        ny[d] = min(max(oy + d - 1, 0), NV - 1) - (Y0 - 1);
    }
#pragma unroll
    for (int p = 0; p < 4; ++p)
        nz[p] = min(max(oz0 + p - 1, 0), NV - 1) - (Z0 - 1);

    float num0 = 0.0f, den0 = 0.0f, num1 = 0.0f, den1 = 0.0f;

#pragma unroll
    for (int p = 0; p < 4; ++p) {  // absolute plane oz0-1+p
#pragma unroll
        for (int iy = 0; iy < 3; ++iy) {
#pragma unroll
            for (int ix = 0; ix < 3; ++ix) {
                float4 q = sq[nz[p]][ny[iy]][nx[ix]];
                if (p <= 2) {  // voxel0: dz = p-1
                    const float SDC =
                        -(float)((p - 1) * (p - 1) + (iy - 1) * (iy - 1) +
                                 (ix - 1) * (ix - 1)) *
                        (LOG2E / (2.0f * 120.0f * 120.0f));
                    float a = c0.x - q.x, b = c0.y - q.y, e = c0.z - q.z;
                    float g = a * a + b * b + e * e;
                    float w = __builtin_amdgcn_exp2f(fmaf(-g, RC, SDC));
                    num0 += w * q.w;
                    den0 += w;
                }
                if (p >= 1) {  // voxel1: dz = p-2
                    const float SDC =
                        -(float)((p - 2) * (p - 2) + (iy - 1) * (iy - 1) +
                                 (ix - 1) * (ix - 1)) *
                        (LOG2E / (2.0f * 120.0f * 120.0f));
                    float a = c1.x - q.x, b = c1.y - q.y, e = c1.z - q.z;
                    float g = a * a + b * b + e * e;
                    float w = __builtin_amdgcn_exp2f(fmaf(-g, RC, SDC));
                    num1 += w * q.w;
                    den1 += w;
                }
            }
        }
    }

    out[oz0 * NV2 + oy * NV + ox] = num0 / fmaxf(den0, 1e-8f);
    out[oz1 * NV2 + oy * NV + ox] = num1 / fmaxf(den1, 1e-8f);
}

extern "C" void kernel_launch(void* const* d_in, const int* in_sizes, int n_in,
                              void* d_out, int out_size, void* d_ws, size_t ws_size,
                              hipStream_t stream) {
    const float* vol = (const float*)d_in[0];
    float* out = (float*)d_out;

    dim3 grid(NV / TX, NV / TY, NV / TZ);  // 3 x 24 x 24 = 1728 blocks
    fused_bilateral_kernel<<<grid, dim3(256), 0, stream>>>(vol, out);
}